// Round 3
// baseline (267.855 us; speedup 1.0000x reference)
//
#include <hip/hip_runtime.h>
#include <math.h>

#define BATCH 64
#define CD 256
#define NX 784
#define TRIU_N 32896
#define MSZ 65536           // elems per swizzled 256x256 matrix
#define REG_STRIDE 1032     // 128 rows * 8 elems + 8 pad (bank-conflict break)
#define ARR_STRIDE 4128     // 4 regions
#define BUF_STRIDE 16512    // 4 arrays (Ahi,Alo,Bhi,Blo)

typedef unsigned short ushort_t;
typedef unsigned int uint_t;
typedef __attribute__((ext_vector_type(8))) short short8;
typedef __attribute__((ext_vector_type(8))) unsigned short ushort8;
typedef __attribute__((ext_vector_type(16))) float floatx16;

__device__ __forceinline__ ushort_t f2bf(float x) {
    uint_t u = __float_as_uint(x);
    u += 0x7fffu + ((u >> 16) & 1u);
    return (ushort_t)(u >> 16);
}
__device__ __forceinline__ float bf2f(ushort_t h) {
    return __uint_as_float(((uint_t)h) << 16);
}
__device__ __forceinline__ void split2(float x, ushort_t& h, ushort_t& l) {
    h = f2bf(x);
    l = f2bf(x - bf2f(h));
}

// swizzled offset of element (r,c) within one 256x256 matrix
__device__ __forceinline__ int swoff(int r, int c) {
    int p = r >> 7, s = (c >> 5) & 7, ks = (c >> 4) & 1, kh = (c >> 3) & 1;
    return ((((p * 8 + s) * 2 + ks) * 2 + kh) * 128 + (r & 127)) * 8 + (c & 7);
}

// raw workgroup barrier (no compiler vmcnt(0) drain); caller must lgkm-wait.
__device__ __forceinline__ void rawbar() {
    __builtin_amdgcn_s_barrier();
    __builtin_amdgcn_sched_barrier(0);
}

// ---------------------------------------------------------------------------
// One BK=32 stage from LDS (gram only): wave computes 2 quadrants.
__device__ __forceinline__ void mfma_stage8(const ushort_t* us, int bufbase,
                                            int wr, int wcp, int khalf, int lrow,
                                            floatx16* acc) {
    __builtin_amdgcn_s_setprio(1);
    #pragma unroll
    for (int ks = 0; ks < 2; ++ks) {
        const int rid = ks * 2 + khalf;
        const ushort_t* rb = us + bufbase + rid * REG_STRIDE + lrow * 8;
        short8 aH = *(const short8*)(rb + wr * 256);
        short8 aL = *(const short8*)(rb + ARR_STRIDE + wr * 256);
        #pragma unroll
        for (int cq = 0; cq < 2; ++cq) {
            const int col = wcp * 2 + cq;
            short8 bH = *(const short8*)(rb + 2 * ARR_STRIDE + col * 256);
            short8 bL = *(const short8*)(rb + 3 * ARR_STRIDE + col * 256);
            acc[cq] = __builtin_amdgcn_mfma_f32_32x32x16_bf16(aH, bH, acc[cq], 0, 0, 0);
            acc[cq] = __builtin_amdgcn_mfma_f32_32x32x16_bf16(aH, bL, acc[cq], 0, 0, 0);
            acc[cq] = __builtin_amdgcn_mfma_f32_32x32x16_bf16(aL, bH, acc[cq], 0, 0, 0);
        }
    }
    __builtin_amdgcn_s_setprio(0);
}

// accumulator -> fsmem bounce (stride 129 -> conflict-free)
__device__ __forceinline__ void acc_bounce(float* fsmem, const floatx16* acc,
                                           int wr, int wcp, int khalf, int lrow) {
    __syncthreads();
    #pragma unroll
    for (int cq = 0; cq < 2; ++cq)
        #pragma unroll
        for (int i = 0; i < 16; ++i) {
            int rl = (i & 3) + ((i >> 2) << 3) + (khalf << 2);
            fsmem[(wr * 32 + rl) * 129 + (wcp * 2 + cq) * 32 + lrow] = acc[cq][i];
        }
    __syncthreads();
}

// ---------------------------------------------------------------------------
// Gram helpers: named-register double buffer (static indexing, rule #20)
struct Cur { float4 v[2][2]; };

__device__ __forceinline__ void gr_load(const float* Xb, int rowBase, int colBase, int s,
                                        const int* side, const int* srow, const int* skq,
                                        Cur& c) {
    #pragma unroll
    for (int q = 0; q < 2; ++q) {
        int gk = s * 32 + skq[q] * 8;
        if (gk < NX) {
            const float* p = Xb + (size_t)((side[q] ? colBase : rowBase) + srow[q]) * NX + gk;
            c.v[q][0] = *(const float4*)p;
            c.v[q][1] = *(const float4*)(p + 4);
        } else {
            c.v[q][0] = make_float4(0.f, 0.f, 0.f, 0.f);
            c.v[q][1] = make_float4(0.f, 0.f, 0.f, 0.f);
        }
    }
}

__device__ __forceinline__ void gr_conv(ushort_t* us, int bufbase, const Cur& c,
                                        const int* side, const int* srow, const int* skq,
                                        float* rs) {
    #pragma unroll
    for (int q = 0; q < 2; ++q) {
        float f[8] = {c.v[q][0].x, c.v[q][0].y, c.v[q][0].z, c.v[q][0].w,
                      c.v[q][1].x, c.v[q][1].y, c.v[q][1].z, c.v[q][1].w};
        rs[q] += ((f[0] + f[1]) + (f[2] + f[3])) + ((f[4] + f[5]) + (f[6] + f[7]));
        uint_t hp[4], lp[4];
        #pragma unroll
        for (int i = 0; i < 4; ++i) {
            ushort_t h0, l0, h1, l1;
            split2(f[2*i], h0, l0); split2(f[2*i+1], h1, l1);
            hp[i] = (uint_t)h0 | ((uint_t)h1 << 16);
            lp[i] = (uint_t)l0 | ((uint_t)l1 << 16);
        }
        int base = bufbase + (side[q] * 2) * ARR_STRIDE + skq[q] * REG_STRIDE + srow[q] * 8;
        *(uint4*)(us + base)              = make_uint4(hp[0], hp[1], hp[2], hp[3]);
        *(uint4*)(us + base + ARR_STRIDE) = make_uint4(lp[0], lp[1], lp[2], lp[3]);
    }
}

// ---------------------------------------------------------------------------
// Gram: Sigma = X X^T / n - m m^T (means fused). 2-stage-ahead load pipeline:
// loads for stage s+2 issue at stage s; conversion of stage s+1 runs under
// stage s's MFMA -> ~1 full stage of latency cover. Raw barriers with
// lgkmcnt(0) only (no vmcnt drain).
__global__ __launch_bounds__(512, 1)
void gram_mfma(const float* __restrict__ X, float* __restrict__ means,
               ushort_t* __restrict__ Gh, ushort_t* __restrict__ Gl) {
    __shared__ __align__(16) float fsmem[16512];   // 66 KB: 2 staging bufs OR epilogue tile
    ushort_t* us = (ushort_t*)fsmem;
    const int bb = blockIdx.y, tile = blockIdx.x;
    const int rowBase = (tile >> 1) * 128, colBase = (tile & 1) * 128;
    const int tid = threadIdx.x, lane = tid & 63, wv = tid >> 6;
    const int wr = wv >> 1, wcp = wv & 1;
    const int khalf = lane >> 5, lrow = lane & 31;
    const float* Xb = X + (size_t)bb * CD * NX;

    floatx16 acc[2];
    #pragma unroll
    for (int cq = 0; cq < 2; ++cq)
        #pragma unroll
        for (int i = 0; i < 16; ++i) acc[cq][i] = 0.f;

    int side[2], srow[2], skq[2];
    #pragma unroll
    for (int q = 0; q < 2; ++q) {
        int gid = q * 512 + tid;
        side[q] = gid >> 9;
        srow[q] = (gid >> 2) & 127;
        skq[q]  = gid & 3;
    }
    float rs[2] = {0.f, 0.f};

    Cur curA, curB;
    gr_load(Xb, rowBase, colBase, 0, side, srow, skq, curA);
    gr_load(Xb, rowBase, colBase, 1, side, srow, skq, curB);
    gr_conv(us, 0, curA, side, srow, skq, rs);          // stage 0 -> buf0

    for (int s = 0; s < 25; s += 2) {
        // ---- even stage s (reads buf0) ----
        asm volatile("s_waitcnt lgkmcnt(0)" ::: "memory");
        rawbar();
        if (s + 2 <= 24) gr_load(Xb, rowBase, colBase, s + 2, side, srow, skq, curA);
        mfma_stage8(us, 0, wr, wcp, khalf, lrow, acc);
        if (s + 1 <= 24) gr_conv(us, BUF_STRIDE, curB, side, srow, skq, rs);  // stage s+1 -> buf1
        // ---- odd stage s+1 (reads buf1) ----
        if (s + 1 <= 24) {
            asm volatile("s_waitcnt lgkmcnt(0)" ::: "memory");
            rawbar();
            if (s + 3 <= 24) gr_load(Xb, rowBase, colBase, s + 3, side, srow, skq, curB);
            mfma_stage8(us, BUF_STRIDE, wr, wcp, khalf, lrow, acc);
            gr_conv(us, 0, curA, side, srow, skq, rs);  // stage s+2 -> buf0 (s+2<=24 here)
        }
    }

    // means: reduce the 4 lanes (skq 0..3) sharing a row; write both panels.
    {
        float r0 = rs[0], r1 = rs[1];
        r0 += __shfl_xor(r0, 1, 64); r0 += __shfl_xor(r0, 2, 64);
        r1 += __shfl_xor(r1, 1, 64); r1 += __shfl_xor(r1, 2, 64);
        if ((tid & 3) == 0) {
            int rr = tid >> 2;
            means[bb * CD + rowBase + rr] = r0 * (1.0f / NX);
            means[bb * CD + colBase + rr] = r1 * (1.0f / NX);
        }
    }

    acc_bounce(fsmem, acc, wr, wcp, khalf, lrow);   // full-drain syncthreads flushes means stores
    const int rloc = tid & 127;
    const int r = rowBase + rloc;
    const float mr = means[bb * CD + r];
    #pragma unroll
    for (int gi = 0; gi < 4; ++gi) {
        int g = (tid >> 7) + gi * 4;
        int c0 = colBase + g * 8;
        int so = swoff(r, c0);
        ushort8 hh, ll;
        #pragma unroll
        for (int j = 0; j < 8; ++j) {
            float v = fsmem[rloc * 129 + g * 8 + j] * (1.0f / NX) - mr * means[bb * CD + c0 + j];
            ushort_t h, l; split2(v, h, l);
            hh[j] = h; ll[j] = l;
        }
        *(ushort8*)(Gh + (size_t)bb * MSZ + so) = hh;
        *(ushort8*)(Gl + (size_t)bb * MSZ + so) = ll;
    }
}

// ---------------------------------------------------------------------------
__global__ __launch_bounds__(64)
void trace_k(const ushort_t* __restrict__ Gh, const ushort_t* __restrict__ Gl,
             float* __restrict__ itr, float* __restrict__ str_) {
    int b = blockIdx.x, lane = threadIdx.x;
    float s = 0.f;
    #pragma unroll
    for (int i = 0; i < 4; ++i) {
        int c = lane + i * 64;
        size_t d = (size_t)b * MSZ + swoff(c, c);
        s += bf2f(Gh[d]) + bf2f(Gl[d]);
    }
    for (int off = 32; off; off >>= 1) s += __shfl_down(s, off, 64);
    if (lane == 0) { itr[b] = 1.0f / s; str_[b] = sqrtf(s); }
}

// ---------------------------------------------------------------------------
// NS GEMM, global-direct: operands are stored in swizzled fragment layout, so
// each wave loads its own MFMA fragments straight from global memory to VGPRs.
// No LDS staging, no barriers, per-wave 2-buffer software pipeline; redundant
// fragment reads (B shared by 4 waves, A by 2) are served by L1/L2.
__device__ __forceinline__ void ns_ldfr(const ushort_t* aHb, const ushort_t* aLb,
                                        const ushort_t* bHb, const ushort_t* bLb,
                                        int s, short8* fa, short8* fb) {
    #pragma unroll
    for (int ks = 0; ks < 2; ++ks) {
        const int off = s * 4096 + ks * 2048;
        fa[ks * 2 + 0] = *(const short8*)(aHb + off);
        fa[ks * 2 + 1] = *(const short8*)(aLb + off);
        #pragma unroll
        for (int cq = 0; cq < 2; ++cq) {
            fb[ks * 4 + cq * 2 + 0] = *(const short8*)(bHb + off + cq * 256);
            fb[ks * 4 + cq * 2 + 1] = *(const short8*)(bLb + off + cq * 256);
        }
    }
}

__device__ __forceinline__ void ns_comp(const short8* fa, const short8* fb, floatx16* acc) {
    __builtin_amdgcn_s_setprio(1);
    #pragma unroll
    for (int ks = 0; ks < 2; ++ks)
        #pragma unroll
        for (int cq = 0; cq < 2; ++cq) {
            acc[cq] = __builtin_amdgcn_mfma_f32_32x32x16_bf16(fa[ks*2+0], fb[ks*4+cq*2+0], acc[cq], 0, 0, 0);
            acc[cq] = __builtin_amdgcn_mfma_f32_32x32x16_bf16(fa[ks*2+0], fb[ks*4+cq*2+1], acc[cq], 0, 0, 0);
            acc[cq] = __builtin_amdgcn_mfma_f32_32x32x16_bf16(fa[ks*2+1], fb[ks*4+cq*2+0], acc[cq], 0, 0, 0);
        }
    __builtin_amdgcn_s_setprio(0);
}

// MODE 0: O1 = acc
// MODE 1: O1 = 1.5*M - 0.5*acc
// MODE 2: y = 1.5*it*M - 0.5*it^2*acc; O1=y; O2 = 1.5*I - 0.5*y
// MODE 3: out_triu = st * (1.5*M - 0.5*acc)
template<int MODE>
__global__ __launch_bounds__(512, 1)
void ns_mfma(const ushort_t* __restrict__ Ah, const ushort_t* __restrict__ Al,
             const ushort_t* __restrict__ Bh, const ushort_t* __restrict__ Bl,
             const ushort_t* __restrict__ Mh, const ushort_t* __restrict__ Ml,
             const float* __restrict__ itr, const float* __restrict__ str_,
             ushort_t* __restrict__ O1h, ushort_t* __restrict__ O1l,
             ushort_t* __restrict__ O2h, ushort_t* __restrict__ O2l,
             float* __restrict__ outT) {
    const int tile = blockIdx.x;
    const int rowBase = (tile >> 1) * 128, colBase = (tile & 1) * 128;
    if (MODE == 3 && rowBase > colBase) return;
    __shared__ __align__(16) float fsmem[16512];   // epilogue bounce only
    const int bb = blockIdx.y;
    const size_t mb = (size_t)bb * MSZ;
    const int tid = threadIdx.x, lane = tid & 63, wv = tid >> 6;
    const int wr = wv >> 1, wcp = wv & 1;
    const int khalf = lane >> 5, lrow = lane & 31;

    // per-thread fragment bases (ushort units); stage s adds s*4096 + ks*2048
    const int fo = khalf * 1024 + lrow * 8;
    const ushort_t* aHb = Ah + mb + (size_t)(rowBase >> 7) * 32768 + fo + wr * 256;
    const ushort_t* aLb = Al + mb + (size_t)(rowBase >> 7) * 32768 + fo + wr * 256;
    const ushort_t* bHb = Bh + mb + (size_t)(colBase >> 7) * 32768 + fo + (wcp * 2) * 256;
    const ushort_t* bLb = Bl + mb + (size_t)(colBase >> 7) * 32768 + fo + (wcp * 2) * 256;

    floatx16 acc[2];
    #pragma unroll
    for (int cq = 0; cq < 2; ++cq)
        #pragma unroll
        for (int i = 0; i < 16; ++i) acc[cq][i] = 0.f;

    short8 faA[4], fbA[8], faB[4], fbB[8];
    ns_ldfr(aHb, aLb, bHb, bLb, 0, faA, fbA);
    ns_ldfr(aHb, aLb, bHb, bLb, 1, faB, fbB);
    #pragma unroll
    for (int s = 0; s < 8; s += 2) {
        ns_comp(faA, fbA, acc);
        if (s + 2 < 8) ns_ldfr(aHb, aLb, bHb, bLb, s + 2, faA, fbA);
        ns_comp(faB, fbB, acc);
        if (s + 3 < 8) ns_ldfr(aHb, aLb, bHb, bLb, s + 3, faB, fbB);
    }

    acc_bounce(fsmem, acc, wr, wcp, khalf, lrow);
    const int rloc = tid & 127;
    const int r = rowBase + rloc;
    float it = 0.f, st = 0.f;
    if (MODE == 2) it = itr[bb];
    if (MODE == 3) st = str_[bb];
    #pragma unroll
    for (int gi = 0; gi < 4; ++gi) {
        int g = (tid >> 7) + gi * 4;
        int c0 = colBase + g * 8;
        int so = swoff(r, c0);
        float v[8];
        #pragma unroll
        for (int j = 0; j < 8; ++j) v[j] = fsmem[rloc * 129 + g * 8 + j];
        if (MODE == 0) {
            ushort8 hh, ll;
            #pragma unroll
            for (int j = 0; j < 8; ++j) {
                ushort_t h, l; split2(v[j], h, l);
                hh[j] = h; ll[j] = l;
            }
            *(ushort8*)(O1h + mb + so) = hh;
            *(ushort8*)(O1l + mb + so) = ll;
        } else {
            ushort8 mh = *(const ushort8*)(Mh + mb + so);
            ushort8 mlv = *(const ushort8*)(Ml + mb + so);
            if (MODE == 1) {
                ushort8 hh, ll;
                #pragma unroll
                for (int j = 0; j < 8; ++j) {
                    float m = bf2f(mh[j]) + bf2f(mlv[j]);
                    float y = fmaf(1.5f, m, -0.5f * v[j]);
                    ushort_t h, l; split2(y, h, l);
                    hh[j] = h; ll[j] = l;
                }
                *(ushort8*)(O1h + mb + so) = hh;
                *(ushort8*)(O1l + mb + so) = ll;
            } else if (MODE == 2) {
                ushort8 yh, yl, zh, zl;
                #pragma unroll
                for (int j = 0; j < 8; ++j) {
                    float m = bf2f(mh[j]) + bf2f(mlv[j]);
                    float y = 1.5f * it * m - 0.5f * it * it * v[j];
                    float z = ((r == c0 + j) ? 1.5f : 0.f) - 0.5f * y;
                    ushort_t h, l;
                    split2(y, h, l); yh[j] = h; yl[j] = l;
                    split2(z, h, l); zh[j] = h; zl[j] = l;
                }
                *(ushort8*)(O1h + mb + so) = yh;
                *(ushort8*)(O1l + mb + so) = yl;
                *(ushort8*)(O2h + mb + so) = zh;
                *(ushort8*)(O2l + mb + so) = zl;
            } else {
                int tb = r * CD - (r * (r - 1)) / 2 - r;
                #pragma unroll
                for (int j = 0; j < 8; ++j) {
                    float m = bf2f(mh[j]) + bf2f(mlv[j]);
                    float y = fmaf(1.5f, m, -0.5f * v[j]);
                    int c = c0 + j;
                    if (c >= r) outT[(size_t)bb * TRIU_N + tb + c] = st * y;
                }
            }
        }
    }
}

// ---------------------------------------------------------------------------
extern "C" void kernel_launch(void* const* d_in, const int* in_sizes, int n_in,
                              void* d_out, int out_size, void* d_ws, size_t ws_size,
                              hipStream_t stream) {
    const float* x = (const float*)d_in[0];
    float* out = (float*)d_out;
    char* ws = (char*)d_ws;
    const size_t HS = (size_t)BATCH * MSZ * 2;   // bytes per matrix array (8 MB)
    ushort_t* S0h = (ushort_t*)(ws + 0 * HS);
    ushort_t* S0l = (ushort_t*)(ws + 1 * HS);
    ushort_t* S1h = (ushort_t*)(ws + 2 * HS);
    ushort_t* S1l = (ushort_t*)(ws + 3 * HS);
    ushort_t* S2h = (ushort_t*)(ws + 4 * HS);
    ushort_t* S2l = (ushort_t*)(ws + 5 * HS);
    ushort_t* S3h = (ushort_t*)(ws + 6 * HS);
    ushort_t* S3l = (ushort_t*)(ws + 7 * HS);
    float* means = (float*)(ws + 8 * HS);
    float* itr = means + BATCH * CD;
    float* str_ = itr + BATCH;

    dim3 gG(4, BATCH);
    gram_mfma<<<gG, 512, 0, stream>>>(x, means, S0h, S0l);              // Sigma -> S0 (means fused)
    trace_k<<<BATCH, 64, 0, stream>>>(S0h, S0l, itr, str_);
    // iter1 (scale folded): Y1 -> S1, Z1 -> S2
    ns_mfma<2><<<gG, 512, 0, stream>>>(S0h, S0l, S0h, S0l, S0h, S0l,
                                       itr, nullptr, S1h, S1l, S2h, S2l, nullptr);
    // T1 = Z1*Y1 -> S3
    ns_mfma<0><<<gG, 512, 0, stream>>>(S2h, S2l, S1h, S1l, nullptr, nullptr,
                                       nullptr, nullptr, S3h, S3l, nullptr, nullptr, nullptr);
    // Y2 = 1.5Y1 - 0.5 Y1*T1 -> S0
    ns_mfma<1><<<gG, 512, 0, stream>>>(S1h, S1l, S3h, S3l, S1h, S1l,
                                       nullptr, nullptr, S0h, S0l, nullptr, nullptr, nullptr);
    // T2 = Z1*Y2 -> S3
    ns_mfma<0><<<gG, 512, 0, stream>>>(S2h, S2l, S0h, S0l, nullptr, nullptr,
                                       nullptr, nullptr, S3h, S3l, nullptr, nullptr, nullptr);
    // Z2 = 1.5Z1 - 0.5 T2*Z1 -> S1  (M = B = Z1)
    ns_mfma<1><<<gG, 512, 0, stream>>>(S3h, S3l, S2h, S2l, S2h, S2l,
                                       nullptr, nullptr, S1h, S1l, nullptr, nullptr, nullptr);
    // T3 = Z2*Y2 -> S3
    ns_mfma<0><<<gG, 512, 0, stream>>>(S1h, S1l, S0h, S0l, nullptr, nullptr,
                                       nullptr, nullptr, S3h, S3l, nullptr, nullptr, nullptr);
    // out = st * (1.5 Y2 - 0.5 Y2*T3), triu-packed
    ns_mfma<3><<<gG, 512, 0, stream>>>(S0h, S0l, S3h, S3l, S0h, S0l,
                                       nullptr, str_, nullptr, nullptr, nullptr, nullptr, out);
}

// Round 4
// 222.257 us; speedup vs baseline: 1.2052x; 1.2052x over previous
//
#include <hip/hip_runtime.h>
#include <math.h>

#define BATCH 64
#define CD 256
#define NX 784
#define TRIU_N 32896
#define MSZ 65536           // elems per swizzled 256x256 matrix
#define REG_STRIDE 1032     // 128 rows * 8 elems + 8 pad (bank-conflict break)
#define ARR_STRIDE 4128     // 4 regions
#define BUF_STRIDE 16512    // 4 arrays (Ahi,Alo,Bhi,Blo)

typedef unsigned short ushort_t;
typedef unsigned int uint_t;
typedef __attribute__((ext_vector_type(8))) short short8;
typedef __attribute__((ext_vector_type(16))) float floatx16;

__device__ __forceinline__ float bf2f(ushort_t h) {
    return __uint_as_float(((uint_t)h) << 16);
}
// pack 2 floats -> (hi-bf16 pair, lo-bf16 pair) via v_cvt_pk_bf16_f32 (RNE,
// bit-identical to the old +0x7fff bit-twiddle, ~6 VALU vs ~16)
__device__ __forceinline__ void pack2(float f0, float f1, uint_t& hp, uint_t& lp) {
    uint_t h, l;
    asm("v_cvt_pk_bf16_f32 %0, %1, %2" : "=v"(h) : "v"(f0), "v"(f1));
    float r0 = f0 - __uint_as_float(h << 16);
    float r1 = f1 - __uint_as_float(h & 0xffff0000u);
    asm("v_cvt_pk_bf16_f32 %0, %1, %2" : "=v"(l) : "v"(r0), "v"(r1));
    hp = h; lp = l;
}
// store 8 fp32 as split-bf16 (hi+lo ushort8)
__device__ __forceinline__ void store8(ushort_t* H, ushort_t* L, const float* y) {
    uint_t hw[4], lw[4];
    #pragma unroll
    for (int i = 0; i < 4; ++i) pack2(y[2*i], y[2*i+1], hw[i], lw[i]);
    *(uint4*)H = make_uint4(hw[0], hw[1], hw[2], hw[3]);
    *(uint4*)L = make_uint4(lw[0], lw[1], lw[2], lw[3]);
}

// swizzled offset of element (r,c) within one 256x256 matrix
__device__ __forceinline__ int swoff(int r, int c) {
    int p = r >> 7, s = (c >> 5) & 7, ks = (c >> 4) & 1, kh = (c >> 3) & 1;
    return ((((p * 8 + s) * 2 + ks) * 2 + kh) * 128 + (r & 127)) * 8 + (c & 7);
}

// raw workgroup barrier (no compiler vmcnt(0) drain); caller must wait first.
__device__ __forceinline__ void rawbar() {
    __builtin_amdgcn_s_barrier();
    __builtin_amdgcn_sched_barrier(0);
}

// ---------------------------------------------------------------------------
// One BK=32 stage from LDS: wave computes 2 quadrants (wr, wcp*2+{0,1}).
__device__ __forceinline__ void mfma_stage8(const ushort_t* us, int bufbase,
                                            int wr, int wcp, int khalf, int lrow,
                                            floatx16* acc) {
    __builtin_amdgcn_s_setprio(1);
    #pragma unroll
    for (int ks = 0; ks < 2; ++ks) {
        const int rid = ks * 2 + khalf;
        const ushort_t* rb = us + bufbase + rid * REG_STRIDE + lrow * 8;
        short8 aH = *(const short8*)(rb + wr * 256);
        short8 aL = *(const short8*)(rb + ARR_STRIDE + wr * 256);
        #pragma unroll
        for (int cq = 0; cq < 2; ++cq) {
            const int col = wcp * 2 + cq;
            short8 bH = *(const short8*)(rb + 2 * ARR_STRIDE + col * 256);
            short8 bL = *(const short8*)(rb + 3 * ARR_STRIDE + col * 256);
            acc[cq] = __builtin_amdgcn_mfma_f32_32x32x16_bf16(aH, bH, acc[cq], 0, 0, 0);
            acc[cq] = __builtin_amdgcn_mfma_f32_32x32x16_bf16(aH, bL, acc[cq], 0, 0, 0);
            acc[cq] = __builtin_amdgcn_mfma_f32_32x32x16_bf16(aL, bH, acc[cq], 0, 0, 0);
        }
    }
    __builtin_amdgcn_s_setprio(0);
}

// accumulator -> fsmem bounce (stride 129 -> conflict-free)
__device__ __forceinline__ void acc_bounce(float* fsmem, const floatx16* acc,
                                           int wr, int wcp, int khalf, int lrow) {
    __syncthreads();
    #pragma unroll
    for (int cq = 0; cq < 2; ++cq)
        #pragma unroll
        for (int i = 0; i < 16; ++i) {
            int rl = (i & 3) + ((i >> 2) << 3) + (khalf << 2);
            fsmem[(wr * 32 + rl) * 129 + (wcp * 2 + cq) * 32 + lrow] = acc[cq][i];
        }
    __syncthreads();
}

// ---------------------------------------------------------------------------
// Gram helpers: named-register double buffer (static indexing, rule #20)
struct Cur { float4 v[2][2]; };

__device__ __forceinline__ void gr_load(const float* Xb, int rowBase, int colBase, int s,
                                        const int* side, const int* srow, const int* skq,
                                        Cur& c) {
    #pragma unroll
    for (int q = 0; q < 2; ++q) {
        int gk = s * 32 + skq[q] * 8;
        if (gk < NX) {
            const float* p = Xb + (size_t)((side[q] ? colBase : rowBase) + srow[q]) * NX + gk;
            c.v[q][0] = *(const float4*)p;
            c.v[q][1] = *(const float4*)(p + 4);
        } else {
            c.v[q][0] = make_float4(0.f, 0.f, 0.f, 0.f);
            c.v[q][1] = make_float4(0.f, 0.f, 0.f, 0.f);
        }
    }
}

__device__ __forceinline__ void gr_conv(ushort_t* us, int bufbase, const Cur& c,
                                        const int* side, const int* srow, const int* skq,
                                        float* rs) {
    #pragma unroll
    for (int q = 0; q < 2; ++q) {
        float f[8] = {c.v[q][0].x, c.v[q][0].y, c.v[q][0].z, c.v[q][0].w,
                      c.v[q][1].x, c.v[q][1].y, c.v[q][1].z, c.v[q][1].w};
        rs[q] += ((f[0] + f[1]) + (f[2] + f[3])) + ((f[4] + f[5]) + (f[6] + f[7]));
        uint_t hp[4], lp[4];
        #pragma unroll
        for (int i = 0; i < 4; ++i) pack2(f[2*i], f[2*i+1], hp[i], lp[i]);
        int base = bufbase + (side[q] * 2) * ARR_STRIDE + skq[q] * REG_STRIDE + srow[q] * 8;
        *(uint4*)(us + base)              = make_uint4(hp[0], hp[1], hp[2], hp[3]);
        *(uint4*)(us + base + ARR_STRIDE) = make_uint4(lp[0], lp[1], lp[2], lp[3]);
    }
}

// ---------------------------------------------------------------------------
// Gram: Sigma = X X^T / n - m m^T. Means fused; trace fused (diag blocks
// atomicAdd f32 partial traces -> tr[bb]; consumers compute 1/tr, sqrt(tr)).
// 2-stage-ahead load pipeline, raw barriers with lgkmcnt(0) only.
__global__ __launch_bounds__(512, 1)
void gram_mfma(const float* __restrict__ X, float* __restrict__ means,
               float* __restrict__ tr,
               ushort_t* __restrict__ Gh, ushort_t* __restrict__ Gl) {
    __shared__ __align__(16) float fsmem[16512];   // 66 KB: 2 staging bufs OR epilogue tile
    __shared__ float dsh[8];
    ushort_t* us = (ushort_t*)fsmem;
    const int bb = blockIdx.y, tile = blockIdx.x;
    const int rowBase = (tile >> 1) * 128, colBase = (tile & 1) * 128;
    const int tid = threadIdx.x, lane = tid & 63, wv = tid >> 6;
    const int wr = wv >> 1, wcp = wv & 1;
    const int khalf = lane >> 5, lrow = lane & 31;
    const float* Xb = X + (size_t)bb * CD * NX;

    floatx16 acc[2];
    #pragma unroll
    for (int cq = 0; cq < 2; ++cq)
        #pragma unroll
        for (int i = 0; i < 16; ++i) acc[cq][i] = 0.f;

    int side[2], srow[2], skq[2];
    #pragma unroll
    for (int q = 0; q < 2; ++q) {
        int gid = q * 512 + tid;
        side[q] = gid >> 9;
        srow[q] = (gid >> 2) & 127;
        skq[q]  = gid & 3;
    }
    float rs[2] = {0.f, 0.f};

    Cur curA, curB;
    gr_load(Xb, rowBase, colBase, 0, side, srow, skq, curA);
    gr_load(Xb, rowBase, colBase, 1, side, srow, skq, curB);
    gr_conv(us, 0, curA, side, srow, skq, rs);          // stage 0 -> buf0

    for (int s = 0; s < 25; s += 2) {
        // ---- even stage s (reads buf0) ----
        asm volatile("s_waitcnt lgkmcnt(0)" ::: "memory");
        rawbar();
        if (s + 2 <= 24) gr_load(Xb, rowBase, colBase, s + 2, side, srow, skq, curA);
        mfma_stage8(us, 0, wr, wcp, khalf, lrow, acc);
        if (s + 1 <= 24) gr_conv(us, BUF_STRIDE, curB, side, srow, skq, rs);
        // ---- odd stage s+1 (reads buf1) ----
        if (s + 1 <= 24) {
            asm volatile("s_waitcnt lgkmcnt(0)" ::: "memory");
            rawbar();
            if (s + 3 <= 24) gr_load(Xb, rowBase, colBase, s + 3, side, srow, skq, curB);
            mfma_stage8(us, BUF_STRIDE, wr, wcp, khalf, lrow, acc);
            gr_conv(us, 0, curA, side, srow, skq, rs);
        }
    }

    // means: reduce the 4 lanes (skq 0..3) sharing a row; write both panels.
    {
        float r0 = rs[0], r1 = rs[1];
        r0 += __shfl_xor(r0, 1, 64); r0 += __shfl_xor(r0, 2, 64);
        r1 += __shfl_xor(r1, 1, 64); r1 += __shfl_xor(r1, 2, 64);
        if ((tid & 3) == 0) {
            int rr = tid >> 2;
            means[bb * CD + rowBase + rr] = r0 * (1.0f / NX);
            means[bb * CD + colBase + rr] = r1 * (1.0f / NX);
        }
    }

    acc_bounce(fsmem, acc, wr, wcp, khalf, lrow);   // full-drain syncthreads flushes means stores
    const int rloc = tid & 127;
    const int r = rowBase + rloc;
    const float mr = means[bb * CD + r];
    const bool diagblk = (rowBase == colBase);
    float dv = 0.f;
    #pragma unroll
    for (int gi = 0; gi < 4; ++gi) {
        int g = (tid >> 7) + gi * 4;
        int c0 = colBase + g * 8;
        int so = swoff(r, c0);
        float v[8];
        #pragma unroll
        for (int j = 0; j < 8; ++j) {
            v[j] = fsmem[rloc * 129 + g * 8 + j] * (1.0f / NX) - mr * means[bb * CD + c0 + j];
            if (diagblk && (c0 + j) == r) dv += v[j];   // static index, runtime cond
        }
        store8(Gh + (size_t)bb * MSZ + so, Gl + (size_t)bb * MSZ + so, v);
    }
    if (diagblk) {
        for (int off = 32; off; off >>= 1) dv += __shfl_down(dv, off, 64);
        if (lane == 0) dsh[wv] = dv;
        __syncthreads();
        if (tid == 0) {
            float s = ((dsh[0] + dsh[1]) + (dsh[2] + dsh[3]))
                    + ((dsh[4] + dsh[5]) + (dsh[6] + dsh[7]));
            atomicAdd(&tr[bb], s);     // 2 diag blocks; fp add commutative -> deterministic
        }
    }
}

// ---------------------------------------------------------------------------
__device__ __forceinline__ void ns_prefetch(const ushort_t* const* arrp, ushort_t* us,
                                            int wv, int lane, int s, int buf) {
    #pragma unroll
    for (int j = 0; j < 4; ++j) {
        int ck = wv * 4 + j;
        int arr = ck >> 3, rid = (ck >> 1) & 3, half = ck & 1;
        const ushort_t* g = arrp[arr] + s * 4096 + rid * 1024 + half * 512 + lane * 8;
        ushort_t* l = us + buf * BUF_STRIDE + arr * ARR_STRIDE + rid * REG_STRIDE + half * 512;
        __builtin_amdgcn_global_load_lds(
            (const __attribute__((address_space(1))) unsigned int*)g,
            (__attribute__((address_space(3))) unsigned int*)l, 16, 0, 0);
    }
}

// NS GEMM on swizzled split-bf16 operands (symmetric => NT). 4-deep LDS
// pipeline with counted vmcnt (proven round-2 structure). Commutativity-
// restructured chain needs only 6 GEMMs:
// MODE 2: y = 1.5*it*M - 0.5*it^2*acc; O1=y; O2 = 1.5*I - 0.5*y   (Y1,Z1)
// MODE 4: O1 = acc (P=Y1^2); O2 = 2.25*I - 1.5*M + 0.25*acc (W=Z1^2)
// MODE 1: O1 = 1.5*M - 0.5*acc   (Y2 and Z2)
// MODE 0: O1 = acc               (R=Y2^2)
// MODE 3: out_triu = sqrt(tr) * (1.5*M - 0.5*acc)   (Y3, packed)
template<int MODE>
__global__ __launch_bounds__(512, 1)
void ns_mfma(const ushort_t* __restrict__ Ah, const ushort_t* __restrict__ Al,
             const ushort_t* __restrict__ Bh, const ushort_t* __restrict__ Bl,
             const ushort_t* __restrict__ Mh, const ushort_t* __restrict__ Ml,
             const float* __restrict__ tr,
             ushort_t* __restrict__ O1h, ushort_t* __restrict__ O1l,
             ushort_t* __restrict__ O2h, ushort_t* __restrict__ O2l,
             float* __restrict__ outT) {
    const int tile = blockIdx.x;
    const int rowBase = (tile >> 1) * 128, colBase = (tile & 1) * 128;
    if (MODE == 3 && rowBase > colBase) return;
    __shared__ __align__(16) float fsmem[33024];   // 132 KB: 4 staging bufs; epilogue overlays
    ushort_t* us = (ushort_t*)fsmem;
    const int bb = blockIdx.y;
    const size_t mb = (size_t)bb * MSZ;
    const int tid = threadIdx.x, lane = tid & 63, wv = tid >> 6;
    const int wr = wv >> 1, wcp = wv & 1;
    const int khalf = lane >> 5, lrow = lane & 31;
    const ushort_t* arrp[4] = {
        Ah + mb + (size_t)(rowBase >> 7) * 32768,
        Al + mb + (size_t)(rowBase >> 7) * 32768,
        Bh + mb + (size_t)(colBase >> 7) * 32768,
        Bl + mb + (size_t)(colBase >> 7) * 32768 };

    floatx16 acc[2];
    #pragma unroll
    for (int cq = 0; cq < 2; ++cq)
        #pragma unroll
        for (int i = 0; i < 16; ++i) acc[cq][i] = 0.f;

    // prologue: 3 stages in flight (12 loads/wave outstanding)
    ns_prefetch(arrp, us, wv, lane, 0, 0);
    ns_prefetch(arrp, us, wv, lane, 1, 1);
    ns_prefetch(arrp, us, wv, lane, 2, 2);
    #pragma unroll
    for (int s = 0; s < 8; ++s) {
        if (s <= 5)      asm volatile("s_waitcnt vmcnt(8)" ::: "memory");
        else if (s == 6) asm volatile("s_waitcnt vmcnt(4)" ::: "memory");
        else             asm volatile("s_waitcnt vmcnt(0)" ::: "memory");
        rawbar();
        mfma_stage8(us, (s & 3) * BUF_STRIDE, wr, wcp, khalf, lrow, acc);
        if (s < 5) ns_prefetch(arrp, us, wv, lane, s + 3, (s + 3) & 3);
    }

    acc_bounce(fsmem, acc, wr, wcp, khalf, lrow);
    const int rloc = tid & 127;
    const int r = rowBase + rloc;
    float it = 0.f, st = 0.f;
    if (MODE == 2) it = 1.0f / tr[bb];
    if (MODE == 3) st = sqrtf(tr[bb]);
    #pragma unroll
    for (int gi = 0; gi < 4; ++gi) {
        int g = (tid >> 7) + gi * 4;
        int c0 = colBase + g * 8;
        int so = swoff(r, c0);
        float v[8];
        #pragma unroll
        for (int j = 0; j < 8; ++j) v[j] = fsmem[rloc * 129 + g * 8 + j];
        if (MODE == 0) {
            store8(O1h + mb + so, O1l + mb + so, v);
        } else {
            float mv[8];
            {
                const ushort_t* mhp = Mh + mb + so;
                const ushort_t* mlp = Ml + mb + so;
                uint4 mh4 = *(const uint4*)mhp;
                uint4 ml4 = *(const uint4*)mlp;
                const uint_t mhw[4] = {mh4.x, mh4.y, mh4.z, mh4.w};
                const uint_t mlw[4] = {ml4.x, ml4.y, ml4.z, ml4.w};
                #pragma unroll
                for (int i = 0; i < 4; ++i) {
                    mv[2*i]   = __uint_as_float(mhw[i] << 16) + __uint_as_float(mlw[i] << 16);
                    mv[2*i+1] = __uint_as_float(mhw[i] & 0xffff0000u) + __uint_as_float(mlw[i] & 0xffff0000u);
                }
            }
            if (MODE == 1) {
                float y[8];
                #pragma unroll
                for (int j = 0; j < 8; ++j) y[j] = fmaf(1.5f, mv[j], -0.5f * v[j]);
                store8(O1h + mb + so, O1l + mb + so, y);
            } else if (MODE == 2) {
                float y[8], z[8];
                #pragma unroll
                for (int j = 0; j < 8; ++j) {
                    y[j] = 1.5f * it * mv[j] - 0.5f * it * it * v[j];
                    z[j] = ((r == c0 + j) ? 1.5f : 0.f) - 0.5f * y[j];
                }
                store8(O1h + mb + so, O1l + mb + so, y);
                store8(O2h + mb + so, O2l + mb + so, z);
            } else if (MODE == 4) {
                float w[8];
                #pragma unroll
                for (int j = 0; j < 8; ++j)
                    w[j] = ((r == c0 + j) ? 2.25f : 0.f) - 1.5f * mv[j] + 0.25f * v[j];
                store8(O1h + mb + so, O1l + mb + so, v);   // P = acc
                store8(O2h + mb + so, O2l + mb + so, w);   // W = Z1^2
            } else {   // MODE 3
                int tb = r * CD - (r * (r - 1)) / 2 - r;
                #pragma unroll
                for (int j = 0; j < 8; ++j) {
                    float y = fmaf(1.5f, mv[j], -0.5f * v[j]);
                    int c = c0 + j;
                    if (c >= r) outT[(size_t)bb * TRIU_N + tb + c] = st * y;
                }
            }
        }
    }
}

// ---------------------------------------------------------------------------
// Chain (all matrices commute: polynomials in A; MFMA k-order makes stored
// iterates exactly symmetric -> NT GEMMs valid):
//   G1: Y1 = 1.5*it*S - 0.5*it^2*S^2 ; Z1 = 1.5I - 0.5*Y1        [mode2]
//   G2: P = Y1^2 ; W = Z1^2 = 2.25I - 1.5*Y1 + 0.25*P (free)     [mode4]
//   G3: Y2 = 1.5*Y1 - 0.5*Z1*P                                    [mode1]
//   G4: Z2 = 1.5*Z1 - 0.5*W*Y2                                    [mode1]
//   G5: R = Y2^2                                                  [mode0]
//   G6: out = sqrt(tr) * (1.5*Y2 - 0.5*Z2*R), triu-packed         [mode3]
extern "C" void kernel_launch(void* const* d_in, const int* in_sizes, int n_in,
                              void* d_out, int out_size, void* d_ws, size_t ws_size,
                              hipStream_t stream) {
    const float* x = (const float*)d_in[0];
    float* out = (float*)d_out;
    char* ws = (char*)d_ws;
    const size_t HS = (size_t)BATCH * MSZ * 2;   // bytes per matrix array (8 MB)
    ushort_t* S0h = (ushort_t*)(ws + 0 * HS);
    ushort_t* S0l = (ushort_t*)(ws + 1 * HS);
    ushort_t* S1h = (ushort_t*)(ws + 2 * HS);
    ushort_t* S1l = (ushort_t*)(ws + 3 * HS);
    ushort_t* S2h = (ushort_t*)(ws + 4 * HS);
    ushort_t* S2l = (ushort_t*)(ws + 5 * HS);
    ushort_t* S3h = (ushort_t*)(ws + 6 * HS);
    ushort_t* S3l = (ushort_t*)(ws + 7 * HS);
    ushort_t* S4h = (ushort_t*)(ws + 8 * HS);
    ushort_t* S4l = (ushort_t*)(ws + 9 * HS);
    float* means = (float*)(ws + 10 * HS);
    float* tr = means + BATCH * CD;

    hipMemsetAsync(tr, 0, BATCH * sizeof(float), stream);
    dim3 gG(4, BATCH);
    // Sigma -> S0 (means + trace fused)
    gram_mfma<<<gG, 512, 0, stream>>>(x, means, tr, S0h, S0l);
    // G1: Y1 -> S1, Z1 -> S2
    ns_mfma<2><<<gG, 512, 0, stream>>>(S0h, S0l, S0h, S0l, S0h, S0l, tr,
                                       S1h, S1l, S2h, S2l, nullptr);
    // G2: P -> S3, W -> S0 (Sigma dead)
    ns_mfma<4><<<gG, 512, 0, stream>>>(S1h, S1l, S1h, S1l, S1h, S1l, tr,
                                       S3h, S3l, S0h, S0l, nullptr);
    // G3: Y2 = 1.5*Y1 - 0.5*Z1*P -> S4
    ns_mfma<1><<<gG, 512, 0, stream>>>(S2h, S2l, S3h, S3l, S1h, S1l, tr,
                                       S4h, S4l, nullptr, nullptr, nullptr);
    // G4: Z2 = 1.5*Z1 - 0.5*W*Y2 -> S1 (Y1 dead)
    ns_mfma<1><<<gG, 512, 0, stream>>>(S0h, S0l, S4h, S4l, S2h, S2l, tr,
                                       S1h, S1l, nullptr, nullptr, nullptr);
    // G5: R = Y2^2 -> S3 (P dead)
    ns_mfma<0><<<gG, 512, 0, stream>>>(S4h, S4l, S4h, S4l, nullptr, nullptr, tr,
                                       S3h, S3l, nullptr, nullptr, nullptr);
    // G6: out = sqrt(tr) * (1.5*Y2 - 0.5*Z2*R), triu-packed
    ns_mfma<3><<<gG, 512, 0, stream>>>(S1h, S1l, S3h, S3l, S4h, S4l, tr,
                                       nullptr, nullptr, nullptr, nullptr, out);
}

// Round 5
// 203.145 us; speedup vs baseline: 1.3185x; 1.0941x over previous
//
#include <hip/hip_runtime.h>
#include <math.h>

#define BATCH 64
#define CD 256
#define NX 784
#define TRIU_N 32896
#define MSZ 65536           // elems per swizzled 256x256 matrix
#define REG_STRIDE 1032     // 128 rows * 8 elems + 8 pad (bank-conflict break)
#define ARR_STRIDE 4128     // 4 regions
#define BUF_STRIDE 16512    // 4 arrays (Ahi,Alo,Bhi,Blo)

typedef unsigned short ushort_t;
typedef unsigned int uint_t;
typedef __attribute__((ext_vector_type(8))) short short8;
typedef __attribute__((ext_vector_type(16))) float floatx16;

// XCD co-location: all 4 tiles of a batch on one XCD (bid%8 == bb%8).
// bid = (bb&7) + 8*((bb>>3)*4 + tile)  -- bijective on [0,256).
// Intra-dispatch: blocks sharing an A/B half-panel sit on the same XCD L2.
// Cross-dispatch: producer and consumer of a batch's matrices share an XCD,
// so NS operand reads are served from that XCD's L2 instead of HBM.
__device__ __forceinline__ void decode_bid(int bid, int& tile, int& bb) {
    int xcd = bid & 7, g = bid >> 3;
    tile = g & 3;
    bb = ((g >> 2) << 3) | xcd;
}

__device__ __forceinline__ float bf2f(ushort_t h) {
    return __uint_as_float(((uint_t)h) << 16);
}
// pack 2 floats -> (hi-bf16 pair, lo-bf16 pair) via v_cvt_pk_bf16_f32
__device__ __forceinline__ void pack2(float f0, float f1, uint_t& hp, uint_t& lp) {
    uint_t h, l;
    asm("v_cvt_pk_bf16_f32 %0, %1, %2" : "=v"(h) : "v"(f0), "v"(f1));
    float r0 = f0 - __uint_as_float(h << 16);
    float r1 = f1 - __uint_as_float(h & 0xffff0000u);
    asm("v_cvt_pk_bf16_f32 %0, %1, %2" : "=v"(l) : "v"(r0), "v"(r1));
    hp = h; lp = l;
}
__device__ __forceinline__ void store8(ushort_t* H, ushort_t* L, const float* y) {
    uint_t hw[4], lw[4];
    #pragma unroll
    for (int i = 0; i < 4; ++i) pack2(y[2*i], y[2*i+1], hw[i], lw[i]);
    *(uint4*)H = make_uint4(hw[0], hw[1], hw[2], hw[3]);
    *(uint4*)L = make_uint4(lw[0], lw[1], lw[2], lw[3]);
}

// swizzled offset of element (r,c) within one 256x256 matrix
__device__ __forceinline__ int swoff(int r, int c) {
    int p = r >> 7, s = (c >> 5) & 7, ks = (c >> 4) & 1, kh = (c >> 3) & 1;
    return ((((p * 8 + s) * 2 + ks) * 2 + kh) * 128 + (r & 127)) * 8 + (c & 7);
}

// raw workgroup barrier (no compiler vmcnt(0) drain); caller must wait first.
__device__ __forceinline__ void rawbar() {
    __builtin_amdgcn_s_barrier();
    __builtin_amdgcn_sched_barrier(0);
}

// ---------------------------------------------------------------------------
// One BK=32 stage from LDS: wave computes 2 quadrants (wr, wcp*2+{0,1}).
__device__ __forceinline__ void mfma_stage8(const ushort_t* us, int bufbase,
                                            int wr, int wcp, int khalf, int lrow,
                                            floatx16* acc) {
    __builtin_amdgcn_s_setprio(1);
    #pragma unroll
    for (int ks = 0; ks < 2; ++ks) {
        const int rid = ks * 2 + khalf;
        const ushort_t* rb = us + bufbase + rid * REG_STRIDE + lrow * 8;
        short8 aH = *(const short8*)(rb + wr * 256);
        short8 aL = *(const short8*)(rb + ARR_STRIDE + wr * 256);
        #pragma unroll
        for (int cq = 0; cq < 2; ++cq) {
            const int col = wcp * 2 + cq;
            short8 bH = *(const short8*)(rb + 2 * ARR_STRIDE + col * 256);
            short8 bL = *(const short8*)(rb + 3 * ARR_STRIDE + col * 256);
            acc[cq] = __builtin_amdgcn_mfma_f32_32x32x16_bf16(aH, bH, acc[cq], 0, 0, 0);
            acc[cq] = __builtin_amdgcn_mfma_f32_32x32x16_bf16(aH, bL, acc[cq], 0, 0, 0);
            acc[cq] = __builtin_amdgcn_mfma_f32_32x32x16_bf16(aL, bH, acc[cq], 0, 0, 0);
        }
    }
    __builtin_amdgcn_s_setprio(0);
}

// accumulator -> fsmem bounce (stride 129 -> conflict-free)
__device__ __forceinline__ void acc_bounce(float* fsmem, const floatx16* acc,
                                           int wr, int wcp, int khalf, int lrow) {
    __syncthreads();
    #pragma unroll
    for (int cq = 0; cq < 2; ++cq)
        #pragma unroll
        for (int i = 0; i < 16; ++i) {
            int rl = (i & 3) + ((i >> 2) << 3) + (khalf << 2);
            fsmem[(wr * 32 + rl) * 129 + (wcp * 2 + cq) * 32 + lrow] = acc[cq][i];
        }
    __syncthreads();
}

// ---------------------------------------------------------------------------
// Gram helpers: named-register double buffer (static indexing, rule #20)
struct Cur { float4 v[2][2]; };

__device__ __forceinline__ void gr_load(const float* Xb, int rowBase, int colBase, int s,
                                        const int* side, const int* srow, const int* skq,
                                        Cur& c) {
    #pragma unroll
    for (int q = 0; q < 2; ++q) {
        int gk = s * 32 + skq[q] * 8;
        if (gk < NX) {
            const float* p = Xb + (size_t)((side[q] ? colBase : rowBase) + srow[q]) * NX + gk;
            c.v[q][0] = *(const float4*)p;
            c.v[q][1] = *(const float4*)(p + 4);
        } else {
            c.v[q][0] = make_float4(0.f, 0.f, 0.f, 0.f);
            c.v[q][1] = make_float4(0.f, 0.f, 0.f, 0.f);
        }
    }
}

__device__ __forceinline__ void gr_conv(ushort_t* us, int bufbase, const Cur& c,
                                        const int* side, const int* srow, const int* skq,
                                        float* rs) {
    #pragma unroll
    for (int q = 0; q < 2; ++q) {
        float f[8] = {c.v[q][0].x, c.v[q][0].y, c.v[q][0].z, c.v[q][0].w,
                      c.v[q][1].x, c.v[q][1].y, c.v[q][1].z, c.v[q][1].w};
        rs[q] += ((f[0] + f[1]) + (f[2] + f[3])) + ((f[4] + f[5]) + (f[6] + f[7]));
        uint_t hp[4], lp[4];
        #pragma unroll
        for (int i = 0; i < 4; ++i) pack2(f[2*i], f[2*i+1], hp[i], lp[i]);
        int base = bufbase + (side[q] * 2) * ARR_STRIDE + skq[q] * REG_STRIDE + srow[q] * 8;
        *(uint4*)(us + base)              = make_uint4(hp[0], hp[1], hp[2], hp[3]);
        *(uint4*)(us + base + ARR_STRIDE) = make_uint4(lp[0], lp[1], lp[2], lp[3]);
    }
}

// ---------------------------------------------------------------------------
// Gram: Sigma = X X^T / n - m m^T. Means + trace fused. 2-stage-ahead load
// pipeline, raw barriers with lgkmcnt(0) only.
__global__ __launch_bounds__(512, 1)
void gram_mfma(const float* __restrict__ X, float* __restrict__ means,
               float* __restrict__ tr,
               ushort_t* __restrict__ Gh, ushort_t* __restrict__ Gl) {
    __shared__ __align__(16) float fsmem[16512];   // 66 KB: 2 staging bufs OR epilogue tile
    __shared__ float dsh[8];
    ushort_t* us = (ushort_t*)fsmem;
    int tile, bb;
    decode_bid(blockIdx.x, tile, bb);
    const int rowBase = (tile >> 1) * 128, colBase = (tile & 1) * 128;
    const int tid = threadIdx.x, lane = tid & 63, wv = tid >> 6;
    const int wr = wv >> 1, wcp = wv & 1;
    const int khalf = lane >> 5, lrow = lane & 31;
    const float* Xb = X + (size_t)bb * CD * NX;

    floatx16 acc[2];
    #pragma unroll
    for (int cq = 0; cq < 2; ++cq)
        #pragma unroll
        for (int i = 0; i < 16; ++i) acc[cq][i] = 0.f;

    int side[2], srow[2], skq[2];
    #pragma unroll
    for (int q = 0; q < 2; ++q) {
        int gid = q * 512 + tid;
        side[q] = gid >> 9;
        srow[q] = (gid >> 2) & 127;
        skq[q]  = gid & 3;
    }
    float rs[2] = {0.f, 0.f};

    Cur curA, curB;
    gr_load(Xb, rowBase, colBase, 0, side, srow, skq, curA);
    gr_load(Xb, rowBase, colBase, 1, side, srow, skq, curB);
    gr_conv(us, 0, curA, side, srow, skq, rs);          // stage 0 -> buf0

    for (int s = 0; s < 25; s += 2) {
        // ---- even stage s (reads buf0) ----
        asm volatile("s_waitcnt lgkmcnt(0)" ::: "memory");
        rawbar();
        if (s + 2 <= 24) gr_load(Xb, rowBase, colBase, s + 2, side, srow, skq, curA);
        mfma_stage8(us, 0, wr, wcp, khalf, lrow, acc);
        if (s + 1 <= 24) gr_conv(us, BUF_STRIDE, curB, side, srow, skq, rs);
        // ---- odd stage s+1 (reads buf1) ----
        if (s + 1 <= 24) {
            asm volatile("s_waitcnt lgkmcnt(0)" ::: "memory");
            rawbar();
            if (s + 3 <= 24) gr_load(Xb, rowBase, colBase, s + 3, side, srow, skq, curB);
            mfma_stage8(us, BUF_STRIDE, wr, wcp, khalf, lrow, acc);
            gr_conv(us, 0, curA, side, srow, skq, rs);
        }
    }

    // means: reduce the 4 lanes (skq 0..3) sharing a row; write both panels.
    {
        float r0 = rs[0], r1 = rs[1];
        r0 += __shfl_xor(r0, 1, 64); r0 += __shfl_xor(r0, 2, 64);
        r1 += __shfl_xor(r1, 1, 64); r1 += __shfl_xor(r1, 2, 64);
        if ((tid & 3) == 0) {
            int rr = tid >> 2;
            means[bb * CD + rowBase + rr] = r0 * (1.0f / NX);
            means[bb * CD + colBase + rr] = r1 * (1.0f / NX);
        }
    }

    acc_bounce(fsmem, acc, wr, wcp, khalf, lrow);   // full-drain syncthreads flushes means stores
    const int rloc = tid & 127;
    const int r = rowBase + rloc;
    const float mr = means[bb * CD + r];
    const bool diagblk = (rowBase == colBase);
    float dv = 0.f;
    #pragma unroll
    for (int gi = 0; gi < 4; ++gi) {
        int g = (tid >> 7) + gi * 4;
        int c0 = colBase + g * 8;
        int so = swoff(r, c0);
        float v[8];
        #pragma unroll
        for (int j = 0; j < 8; ++j) {
            v[j] = fsmem[rloc * 129 + g * 8 + j] * (1.0f / NX) - mr * means[bb * CD + c0 + j];
            if (diagblk && (c0 + j) == r) dv += v[j];
        }
        store8(Gh + (size_t)bb * MSZ + so, Gl + (size_t)bb * MSZ + so, v);
    }
    if (diagblk) {
        for (int off = 32; off; off >>= 1) dv += __shfl_down(dv, off, 64);
        if (lane == 0) dsh[wv] = dv;
        __syncthreads();
        if (tid == 0) {
            float s = ((dsh[0] + dsh[1]) + (dsh[2] + dsh[3]))
                    + ((dsh[4] + dsh[5]) + (dsh[6] + dsh[7]));
            atomicAdd(&tr[bb], s);
        }
    }
}

// ---------------------------------------------------------------------------
__device__ __forceinline__ void ns_prefetch(const ushort_t* const* arrp, ushort_t* us,
                                            int wv, int lane, int s, int buf) {
    #pragma unroll
    for (int j = 0; j < 4; ++j) {
        int ck = wv * 4 + j;
        int arr = ck >> 3, rid = (ck >> 1) & 3, half = ck & 1;
        const ushort_t* g = arrp[arr] + s * 4096 + rid * 1024 + half * 512 + lane * 8;
        ushort_t* l = us + buf * BUF_STRIDE + arr * ARR_STRIDE + rid * REG_STRIDE + half * 512;
        __builtin_amdgcn_global_load_lds(
            (const __attribute__((address_space(1))) unsigned int*)g,
            (__attribute__((address_space(3))) unsigned int*)l, 16, 0, 0);
    }
}

// NS GEMM on swizzled split-bf16 operands (symmetric => NT). 4-deep LDS
// pipeline with counted vmcnt. 6-GEMM commutativity-restructured chain:
// MODE 2: y = 1.5*it*M - 0.5*it^2*acc; O1=y; O2 = 1.5*I - 0.5*y   (Y1,Z1)
// MODE 4: O1 = acc (P=Y1^2); O2 = 2.25*I - 1.5*M + 0.25*acc (W=Z1^2)
// MODE 1: O1 = 1.5*M - 0.5*acc   (Y2 and Z2)
// MODE 0: O1 = acc               (R=Y2^2)
// MODE 3: out_triu = sqrt(tr) * (1.5*M - 0.5*acc)   (Y3, packed)
template<int MODE>
__global__ __launch_bounds__(512, 1)
void ns_mfma(const ushort_t* __restrict__ Ah, const ushort_t* __restrict__ Al,
             const ushort_t* __restrict__ Bh, const ushort_t* __restrict__ Bl,
             const ushort_t* __restrict__ Mh, const ushort_t* __restrict__ Ml,
             const float* __restrict__ tr,
             ushort_t* __restrict__ O1h, ushort_t* __restrict__ O1l,
             ushort_t* __restrict__ O2h, ushort_t* __restrict__ O2l,
             float* __restrict__ outT) {
    int tile, bb;
    decode_bid(blockIdx.x, tile, bb);
    const int rowBase = (tile >> 1) * 128, colBase = (tile & 1) * 128;
    if (MODE == 3 && rowBase > colBase) return;
    __shared__ __align__(16) float fsmem[33024];   // 132 KB: 4 staging bufs; epilogue overlays
    ushort_t* us = (ushort_t*)fsmem;
    const size_t mb = (size_t)bb * MSZ;
    const int tid = threadIdx.x, lane = tid & 63, wv = tid >> 6;
    const int wr = wv >> 1, wcp = wv & 1;
    const int khalf = lane >> 5, lrow = lane & 31;
    const ushort_t* arrp[4] = {
        Ah + mb + (size_t)(rowBase >> 7) * 32768,
        Al + mb + (size_t)(rowBase >> 7) * 32768,
        Bh + mb + (size_t)(colBase >> 7) * 32768,
        Bl + mb + (size_t)(colBase >> 7) * 32768 };

    floatx16 acc[2];
    #pragma unroll
    for (int cq = 0; cq < 2; ++cq)
        #pragma unroll
        for (int i = 0; i < 16; ++i) acc[cq][i] = 0.f;

    // prologue: 3 stages in flight (12 loads/wave outstanding)
    ns_prefetch(arrp, us, wv, lane, 0, 0);
    ns_prefetch(arrp, us, wv, lane, 1, 1);
    ns_prefetch(arrp, us, wv, lane, 2, 2);
    #pragma unroll
    for (int s = 0; s < 8; ++s) {
        if (s <= 5)      asm volatile("s_waitcnt vmcnt(8)" ::: "memory");
        else if (s == 6) asm volatile("s_waitcnt vmcnt(4)" ::: "memory");
        else             asm volatile("s_waitcnt vmcnt(0)" ::: "memory");
        rawbar();
        mfma_stage8(us, (s & 3) * BUF_STRIDE, wr, wcp, khalf, lrow, acc);
        if (s < 5) ns_prefetch(arrp, us, wv, lane, s + 3, (s + 3) & 3);
    }

    acc_bounce(fsmem, acc, wr, wcp, khalf, lrow);
    const int rloc = tid & 127;
    const int r = rowBase + rloc;
    float it = 0.f, st = 0.f;
    if (MODE == 2) it = 1.0f / tr[bb];
    if (MODE == 3) st = sqrtf(tr[bb]);
    #pragma unroll
    for (int gi = 0; gi < 4; ++gi) {
        int g = (tid >> 7) + gi * 4;
        int c0 = colBase + g * 8;
        int so = swoff(r, c0);
        float v[8];
        #pragma unroll
        for (int j = 0; j < 8; ++j) v[j] = fsmem[rloc * 129 + g * 8 + j];
        if (MODE == 0) {
            store8(O1h + mb + so, O1l + mb + so, v);
        } else {
            float mv[8];
            {
                const ushort_t* mhp = Mh + mb + so;
                const ushort_t* mlp = Ml + mb + so;
                uint4 mh4 = *(const uint4*)mhp;
                uint4 ml4 = *(const uint4*)mlp;
                const uint_t mhw[4] = {mh4.x, mh4.y, mh4.z, mh4.w};
                const uint_t mlw[4] = {ml4.x, ml4.y, ml4.z, ml4.w};
                #pragma unroll
                for (int i = 0; i < 4; ++i) {
                    mv[2*i]   = __uint_as_float(mhw[i] << 16) + __uint_as_float(mlw[i] << 16);
                    mv[2*i+1] = __uint_as_float(mhw[i] & 0xffff0000u) + __uint_as_float(mlw[i] & 0xffff0000u);
                }
            }
            if (MODE == 1) {
                float y[8];
                #pragma unroll
                for (int j = 0; j < 8; ++j) y[j] = fmaf(1.5f, mv[j], -0.5f * v[j]);
                store8(O1h + mb + so, O1l + mb + so, y);
            } else if (MODE == 2) {
                float y[8], z[8];
                #pragma unroll
                for (int j = 0; j < 8; ++j) {
                    y[j] = 1.5f * it * mv[j] - 0.5f * it * it * v[j];
                    z[j] = ((r == c0 + j) ? 1.5f : 0.f) - 0.5f * y[j];
                }
                store8(O1h + mb + so, O1l + mb + so, y);
                store8(O2h + mb + so, O2l + mb + so, z);
            } else if (MODE == 4) {
                float w[8];
                #pragma unroll
                for (int j = 0; j < 8; ++j)
                    w[j] = ((r == c0 + j) ? 2.25f : 0.f) - 1.5f * mv[j] + 0.25f * v[j];
                store8(O1h + mb + so, O1l + mb + so, v);   // P = acc
                store8(O2h + mb + so, O2l + mb + so, w);   // W = Z1^2
            } else {   // MODE 3
                int tb = r * CD - (r * (r - 1)) / 2 - r;
                #pragma unroll
                for (int j = 0; j < 8; ++j) {
                    float y = fmaf(1.5f, mv[j], -0.5f * v[j]);
                    int c = c0 + j;
                    if (c >= r) outT[(size_t)bb * TRIU_N + tb + c] = st * y;
                }
            }
        }
    }
}

// ---------------------------------------------------------------------------
// Chain (all matrices commute: polynomials in A; MFMA k-order makes stored
// iterates exactly symmetric -> NT GEMMs valid):
//   G1: Y1 = 1.5*it*S - 0.5*it^2*S^2 ; Z1 = 1.5I - 0.5*Y1        [mode2]
//   G2: P = Y1^2 ; W = Z1^2 = 2.25I - 1.5*Y1 + 0.25*P (free)     [mode4]
//   G3: Y2 = 1.5*Y1 - 0.5*Z1*P                                    [mode1]
//   G4: Z2 = 1.5*Z1 - 0.5*W*Y2                                    [mode1]
//   G5: R = Y2^2                                                  [mode0]
//   G6: out = sqrt(tr) * (1.5*Y2 - 0.5*Z2*R), triu-packed         [mode3]
extern "C" void kernel_launch(void* const* d_in, const int* in_sizes, int n_in,
                              void* d_out, int out_size, void* d_ws, size_t ws_size,
                              hipStream_t stream) {
    const float* x = (const float*)d_in[0];
    float* out = (float*)d_out;
    char* ws = (char*)d_ws;
    const size_t HS = (size_t)BATCH * MSZ * 2;   // bytes per matrix array (8 MB)
    ushort_t* S0h = (ushort_t*)(ws + 0 * HS);
    ushort_t* S0l = (ushort_t*)(ws + 1 * HS);
    ushort_t* S1h = (ushort_t*)(ws + 2 * HS);
    ushort_t* S1l = (ushort_t*)(ws + 3 * HS);
    ushort_t* S2h = (ushort_t*)(ws + 4 * HS);
    ushort_t* S2l = (ushort_t*)(ws + 5 * HS);
    ushort_t* S3h = (ushort_t*)(ws + 6 * HS);
    ushort_t* S3l = (ushort_t*)(ws + 7 * HS);
    ushort_t* S4h = (ushort_t*)(ws + 8 * HS);
    ushort_t* S4l = (ushort_t*)(ws + 9 * HS);
    float* means = (float*)(ws + 10 * HS);
    float* tr = means + BATCH * CD;

    hipMemsetAsync(tr, 0, BATCH * sizeof(float), stream);
    // Sigma -> S0 (means + trace fused)
    gram_mfma<<<256, 512, 0, stream>>>(x, means, tr, S0h, S0l);
    // G1: Y1 -> S1, Z1 -> S2
    ns_mfma<2><<<256, 512, 0, stream>>>(S0h, S0l, S0h, S0l, S0h, S0l, tr,
                                        S1h, S1l, S2h, S2l, nullptr);
    // G2: P -> S3, W -> S0 (Sigma dead)
    ns_mfma<4><<<256, 512, 0, stream>>>(S1h, S1l, S1h, S1l, S1h, S1l, tr,
                                        S3h, S3l, S0h, S0l, nullptr);
    // G3: Y2 = 1.5*Y1 - 0.5*Z1*P -> S4
    ns_mfma<1><<<256, 512, 0, stream>>>(S2h, S2l, S3h, S3l, S1h, S1l, tr,
                                        S4h, S4l, nullptr, nullptr, nullptr);
    // G4: Z2 = 1.5*Z1 - 0.5*W*Y2 -> S1 (Y1 dead)
    ns_mfma<1><<<256, 512, 0, stream>>>(S0h, S0l, S4h, S4l, S2h, S2l, tr,
                                        S1h, S1l, nullptr, nullptr, nullptr);
    // G5: R = Y2^2 -> S3 (P dead)
    ns_mfma<0><<<256, 512, 0, stream>>>(S4h, S4l, S4h, S4l, nullptr, nullptr, tr,
                                        S3h, S3l, nullptr, nullptr, nullptr);
    // G6: out = sqrt(tr) * (1.5*Y2 - 0.5*Z2*R), triu-packed
    ns_mfma<3><<<256, 512, 0, stream>>>(S1h, S1l, S3h, S3l, S4h, S4l, tr,
                                        nullptr, nullptr, nullptr, nullptr, out);
}